// Round 1
// baseline (10912.980 us; speedup 1.0000x reference)
//
#include <hip/hip_runtime.h>
#include <hip/hip_bf16.h>
#include <stdint.h>

#define SQ   2048
#define NB   8
#define G4   1024
#define NROW 16384   // SQ*NB

typedef float f32x4 __attribute__((ext_vector_type(4)));
typedef short bf16x8 __attribute__((ext_vector_type(8)));
typedef uint32_t u32;

// ---------------- helpers ----------------
__device__ __forceinline__ f32x4 mfma16(bf16x8 a, bf16x8 b, f32x4 c) {
  return __builtin_amdgcn_mfma_f32_16x16x32_bf16(a, b, c, 0, 0, 0);
}
__device__ __forceinline__ u32 pk_bf16(float lo, float hi) {
  u32 r;
  asm("v_cvt_pk_bf16_f32 %0, %1, %2" : "=v"(r) : "v"(lo), "v"(hi));
  return r;
}
__device__ __forceinline__ float bf_lo(u32 u){ union{u32 a; float f;} x; x.a = u << 16;        return x.f; }
__device__ __forceinline__ float bf_hi(u32 u){ union{u32 a; float f;} x; x.a = u & 0xffff0000u; return x.f; }

typedef __attribute__((address_space(3))) u32 lds_u32_t;
typedef __attribute__((address_space(1))) const u32 glb_u32_t;
__device__ __forceinline__ void gload_lds16(const void* g, void* l) {
  __builtin_amdgcn_global_load_lds((glb_u32_t*)g, (lds_u32_t*)l, 16, 0, 0);
}

__device__ __forceinline__ float sigm(float x)   { return 1.0f / (1.0f + __expf(-x)); }
__device__ __forceinline__ float tanh_f(float x) { return 1.0f - 2.0f / (__expf(2.0f * x) + 1.0f); }
__device__ __forceinline__ float swz_x8(float x) {       // exchange with lane^8
  union { float f; int i; } a, b; a.f = x;
  b.i = __builtin_amdgcn_ds_swizzle(a.i, 0x201F);
  return b.f;
}

// =====================================================================
// Kernel 1: x_proj = x @ Wih^T + bih  -> bf16, layout [dir][t*8+b][1024g],
// bytes within each 2KB row XOR-swizzled by ((m&7)<<4) so the recurrent
// kernel's linear global_load_lds slab gives bank-conflict-free reads.
// M = g (1024, blockIdx.y*128), N = m = t*8+b (16384, blockIdx.x*128)
// =====================================================================
__global__ __launch_bounds__(256) void xproj_gemm(
    const float* __restrict__ x,
    const float* __restrict__ WihF, const float* __restrict__ bihF,
    const float* __restrict__ WihB, const float* __restrict__ bihB,
    uint16_t* __restrict__ xp)
{
  const int dir = blockIdx.z;
  const float* Wih = dir ? WihB : WihF;
  const float* bih = dir ? bihB : bihF;
  char* xpd = (char*)xp + (size_t)dir * ((size_t)NROW * G4 * 2);

  const int g0 = blockIdx.y * 128;
  const int m0 = blockIdx.x * 128;

  __shared__ union {
    struct { short A[128 * 72]; short B[128 * 72]; } s;  // 144B row pitch (bank-safe)
    short T[128 * 136];                                  // 272B row pitch transpose stage
  } u;
  __shared__ float biasS[128];

  const int tid  = threadIdx.x;
  const int lane = tid & 63;
  const int w    = tid >> 6;
  const int wg   = w >> 1;          // g-half of 128x128 tile
  const int wm   = w & 1;           // m-half
  const int l15  = lane & 15;
  const int l4   = lane >> 4;

  if (tid < 128) biasS[tid] = bih[g0 + tid];

  f32x4 acc[4][4] = {};

  const int r_st = tid >> 1;
  const int half = tid & 1;
  const int mrow_st = m0 + r_st;
  const int xb = mrow_st & 7;         // batch
  const int xt = mrow_st >> 3;        // time
  const float* xrow = x + ((size_t)xb * SQ + xt) * 256;
  const float* wrow = Wih + (size_t)(g0 + r_st) * 256;

  for (int s = 0; s < 4; ++s) {       // K in 4 chunks of 64
    const int k0 = s * 64;
    __syncthreads();
    {   // stage A (Wih rows) and B (x rows), f32 -> bf16
      const float* srcA = wrow + k0 + half * 32;
      const float* srcB = xrow + k0 + half * 32;
      short* dstA = u.s.A + r_st * 72 + half * 32;
      short* dstB = u.s.B + r_st * 72 + half * 32;
      #pragma unroll
      for (int j = 0; j < 4; ++j) {
        f32x4 a0 = *(const f32x4*)(srcA + j * 8);
        f32x4 a1 = *(const f32x4*)(srcA + j * 8 + 4);
        uint4 pa = { pk_bf16(a0.x, a0.y), pk_bf16(a0.z, a0.w),
                     pk_bf16(a1.x, a1.y), pk_bf16(a1.z, a1.w) };
        *(uint4*)(dstA + j * 8) = pa;
        f32x4 b0 = *(const f32x4*)(srcB + j * 8);
        f32x4 b1 = *(const f32x4*)(srcB + j * 8 + 4);
        uint4 pb = { pk_bf16(b0.x, b0.y), pk_bf16(b0.z, b0.w),
                     pk_bf16(b1.x, b1.y), pk_bf16(b1.z, b1.w) };
        *(uint4*)(dstB + j * 8) = pb;
      }
    }
    __syncthreads();
    #pragma unroll
    for (int kt = 0; kt < 2; ++kt) {
      bf16x8 aF[4], bF[4];
      #pragma unroll
      for (int i = 0; i < 4; ++i) {
        const int ar = wg * 64 + i * 16 + l15;
        const int br = wm * 64 + i * 16 + l15;
        aF[i] = *(const bf16x8*)(u.s.A + ar * 72 + kt * 32 + l4 * 8);
        bF[i] = *(const bf16x8*)(u.s.B + br * 72 + kt * 32 + l4 * 8);
      }
      #pragma unroll
      for (int i = 0; i < 4; ++i)
        #pragma unroll
        for (int j = 0; j < 4; ++j)
          acc[i][j] = mfma16(aF[i], bF[j], acc[i][j]);
    }
  }

  // epilogue: bias + bf16 + transpose-stage (lane holds 4 consecutive g for one m)
  __syncthreads();
  #pragma unroll
  for (int i = 0; i < 4; ++i) {
    const f32x4 bv = *(const f32x4*)(biasS + wg * 64 + i * 16 + l4 * 4);
    #pragma unroll
    for (int j = 0; j < 4; ++j) {
      f32x4 v = acc[i][j];
      v.x += bv.x; v.y += bv.y; v.z += bv.z; v.w += bv.w;
      const int mrow = wm * 64 + j * 16 + l15;
      const int gcol = wg * 64 + i * 16 + l4 * 4;
      uint2 p; p.x = pk_bf16(v.x, v.y); p.y = pk_bf16(v.z, v.w);
      *(uint2*)(u.T + mrow * 136 + gcol) = p;
    }
  }
  __syncthreads();
  {   // linear coalesced store, XOR-pre-swizzle destination within each 2KB row
    const char* trow = (const char*)(u.T + r_st * 136);
    char* orow = xpd + (size_t)(m0 + r_st) * 2048 + g0 * 2;
    const int sw = (r_st & 7) << 4;
    #pragma unroll
    for (int j = 0; j < 8; ++j) {
      const int local = half * 128 + j * 16;
      uint4 v = *(const uint4*)(trow + local);
      *(uint4*)(orow + (local ^ sw)) = v;
    }
  }
}

// =====================================================================
// Kernel 2: the sequential bidirectional LSTM scan.
// grid = 2 (one WG per direction), 256 threads = 4 waves, 1 wave/SIMD.
// Whh resident on-chip: gates i,f,g as 384 persistent VGPR A-fragments,
// o-gate (256 rows) bf16 in LDS (XOR swizzled). h kept as bf16 in LDS
// ("hT", 8 rows x 512B). xp slab (16KB/step) streamed via global_load_lds.
// =====================================================================
__global__ __launch_bounds__(256, 1) void lstm_rec(
    const float* __restrict__ WhhF,
    const float* __restrict__ WhhB,
    const uint16_t* __restrict__ xp,
    float* __restrict__ out)
{
  extern __shared__ char smem[];
  char* Wlds = smem;                  // 131072B: o-gate weights
  char* hTm  = smem + 131072;         // 4096B:   h bf16 [b][256k]
  char* xpB  = smem + 131072 + 4096;  // 16384B:  xp slab [b][1024g] bf16

  const int dir = blockIdx.x;
  const float* Whh = dir ? WhhB : WhhF;
  const char* xpd = (const char*)xp + (size_t)dir * ((size_t)NROW * G4 * 2);

  const int tid  = threadIdx.x;
  const int lane = tid & 63;
  const int w    = tid >> 6;
  const int l15  = lane & 15;
  const int l4   = lane >> 4;
  const int bcl  = lane & 7;           // batch (clamped)
  const int qsel = (lane >> 3) & 1;    // 0: lane owns real batch col; 1: helper lane

  // ---- persistent register A-fragments for gates i,f,g (M-tiles 0..47)
  bf16x8 regA[3][4][8];
  #pragma unroll
  for (int gq = 0; gq < 3; ++gq) {
    #pragma unroll
    for (int qq = 0; qq < 4; ++qq) {
      const int mt = gq * 16 + w * 4 + qq;
      const float* src = Whh + (size_t)(mt * 16 + l15) * 256 + l4 * 8;
      #pragma unroll
      for (int kt = 0; kt < 8; ++kt) {
        f32x4 v0 = *(const f32x4*)(src + kt * 32);
        f32x4 v1 = *(const f32x4*)(src + kt * 32 + 4);
        union { bf16x8 v; u32 u[4]; } pk;
        pk.u[0] = pk_bf16(v0.x, v0.y); pk.u[1] = pk_bf16(v0.z, v0.w);
        pk.u[2] = pk_bf16(v1.x, v1.y); pk.u[3] = pk_bf16(v1.z, v1.w);
        regA[gq][qq][kt] = pk.v;
      }
    }
  }

  // ---- stage o-gate weights (Whh rows 768..1023) into LDS, XOR swizzled
  {
    const float* src = Whh + (size_t)(768 + tid) * 256;
    char* drow = Wlds + tid * 512;
    const int sw = (tid & 7) << 4;
    #pragma unroll 4
    for (int c = 0; c < 32; ++c) {
      f32x4 v0 = *(const f32x4*)(src + c * 8);
      f32x4 v1 = *(const f32x4*)(src + c * 8 + 4);
      uint4 p = { pk_bf16(v0.x, v0.y), pk_bf16(v0.z, v0.w),
                  pk_bf16(v1.x, v1.y), pk_bf16(v1.z, v1.w) };
      *(uint4*)(drow + ((c * 16) ^ sw)) = p;
    }
  }
  // h(0) = 0
  { uint4 z = make_uint4(0,0,0,0); *(uint4*)(hTm + tid * 16) = z; }
  // prologue: first xp slab
  {
    const char* g = xpd + (size_t)(dir ? (SQ - 1) : 0) * 16384;
    #pragma unroll
    for (int it = 0; it < 4; ++it)
      gload_lds16(g + it * 4096 + w * 1024 + lane * 16, xpB + it * 4096 + w * 1024);
  }
  float cst[8] = {0,0,0,0,0,0,0,0};
  __syncthreads();

  #pragma unroll 1
  for (int step = 0; step < SQ; ++step) {
    const int tt = dir ? (SQ - 1 - step) : step;

    // ---- acc init = x-projection (+bias, already folded)
    f32x4 acc[4][4];
    #pragma unroll
    for (int gq = 0; gq < 4; ++gq) {
      #pragma unroll
      for (int qq = 0; qq < 4; ++qq) {
        const int grow = (gq * 16 + w * 4 + qq) * 16 + l4 * 4;
        const uint2 d = *(const uint2*)(xpB + bcl * 2048 + ((grow * 2) ^ (bcl << 4)));
        f32x4 t; t.x = bf_lo(d.x); t.y = bf_hi(d.x); t.z = bf_lo(d.y); t.w = bf_hi(d.y);
        acc[gq][qq] = t;
      }
    }
    __syncthreads();   // B1: all waves done reading xpB -> safe to overwrite

    // ---- prefetch next slab (lands by B2; read next step)
    {
      const int ttn = dir ? (tt > 0 ? tt - 1 : 0) : (tt < SQ - 1 ? tt + 1 : SQ - 1);
      const char* g = xpd + (size_t)ttn * 16384;
      #pragma unroll
      for (int it = 0; it < 4; ++it)
        gload_lds16(g + it * 4096 + w * 1024 + lane * 16, xpB + it * 4096 + w * 1024);
    }

    // ---- gates += Whh * h   (512 MFMAs across 4 waves)
    #pragma unroll
    for (int kt = 0; kt < 8; ++kt) {
      const int koff = kt * 64 + l4 * 16;
      const bf16x8 bF = *(const bf16x8*)(hTm + bcl * 512 + (koff ^ (bcl << 4)));
      bf16x8 a3[4];
      #pragma unroll
      for (int qq = 0; qq < 4; ++qq) {
        const int r = (w * 4 + qq) * 16 + l15;
        a3[qq] = *(const bf16x8*)(Wlds + r * 512 + (koff ^ ((r & 7) << 4)));
      }
      #pragma unroll
      for (int gq = 0; gq < 3; ++gq)
        #pragma unroll
        for (int qq = 0; qq < 4; ++qq)
          acc[gq][qq] = mfma16(regA[gq][qq][kt], bF, acc[gq][qq]);
      #pragma unroll
      for (int qq = 0; qq < 4; ++qq)
        acc[3][qq] = mfma16(a3[qq], bF, acc[3][qq]);
    }
    __syncthreads();   // B2: hT reads done; xp prefetch drained

    // ---- redistribute: valid lanes (b<8) keep quads 0,1; lane^8 takes quads 2,3
    f32x4 P[4][2];
    #pragma unroll
    for (int gq = 0; gq < 4; ++gq) {
      #pragma unroll
      for (int k = 0; k < 2; ++k) {
        f32x4 own = acc[gq][k];
        f32x4 rec;
        #pragma unroll
        for (int e = 0; e < 4; ++e) rec[e] = swz_x8(acc[gq][2 + k][e]);
        #pragma unroll
        for (int e = 0; e < 4; ++e) P[gq][k][e] = qsel ? rec[e] : own[e];
      }
    }

    // ---- activations + state update + h writes (all 64 lanes useful)
    #pragma unroll
    for (int k = 0; k < 2; ++k) {
      f32x4 hv;
      #pragma unroll
      for (int e = 0; e < 4; ++e) {
        const float iv = sigm(P[0][k][e]);
        const float fv = sigm(P[1][k][e]);
        const float gv = tanh_f(P[2][k][e]);
        const float ov = sigm(P[3][k][e]);
        const float cv = fv * cst[k * 4 + e] + iv * gv;
        cst[k * 4 + e] = cv;
        hv[e] = ov * tanh_f(cv);
      }
      const int qe = qsel * 2 + k;
      const int j0 = (w * 4 + qe) * 16 + l4 * 4;
      uint2 hp; hp.x = pk_bf16(hv.x, hv.y); hp.y = pk_bf16(hv.z, hv.w);
      *(uint2*)(hTm + bcl * 512 + ((j0 * 2) ^ (bcl << 4))) = hp;
      float* op = out + ((size_t)(bcl * SQ + tt)) * 512 + dir * 256 + j0;
      *(f32x4*)op = hv;
    }
    __syncthreads();   // B3: h(t+1) visible before next step's reads
  }
}

// =====================================================================
extern "C" void kernel_launch(void* const* d_in, const int* in_sizes, int n_in,
                              void* d_out, int out_size, void* d_ws, size_t ws_size,
                              hipStream_t stream) {
  const float* x    = (const float*)d_in[0];
  const float* WihF = (const float*)d_in[1];
  const float* bihF = (const float*)d_in[2];
  const float* WhhF = (const float*)d_in[3];
  const float* WihB = (const float*)d_in[4];
  const float* bihB = (const float*)d_in[5];
  const float* WhhB = (const float*)d_in[6];
  float* out = (float*)d_out;
  uint16_t* xpw = (uint16_t*)d_ws;

  // need 2 * 16384 * 1024 * 2B = 64 MiB of workspace for bf16 x-projection
  if (ws_size < (size_t)2 * NROW * G4 * 2) return;

  (void)hipFuncSetAttribute((const void*)lstm_rec,
                            hipFuncAttributeMaxDynamicSharedMemorySize, 151552);

  xproj_gemm<<<dim3(128, 8, 2), dim3(256), 0, stream>>>(x, WihF, bihF, WihB, bihB, xpw);
  lstm_rec<<<dim3(2), dim3(256), 151552, stream>>>(WhhF, WhhB, xpw, out);
}

// Round 2
// 8617.639 us; speedup vs baseline: 1.2664x; 1.2664x over previous
//
#include <hip/hip_runtime.h>
#include <hip/hip_bf16.h>
#include <stdint.h>

#define SQ   2048
#define NB   8
#define G4   1024
#define NROW 16384   // SQ*NB

typedef float f32x4 __attribute__((ext_vector_type(4)));
typedef short bf16x8 __attribute__((ext_vector_type(8)));
typedef uint32_t u32;

// ---------------- helpers ----------------
__device__ __forceinline__ f32x4 mfma16(bf16x8 a, bf16x8 b, f32x4 c) {
  return __builtin_amdgcn_mfma_f32_16x16x32_bf16(a, b, c, 0, 0, 0);
}
__device__ __forceinline__ u32 pk_bf16(float lo, float hi) {
  u32 r;
  asm("v_cvt_pk_bf16_f32 %0, %1, %2" : "=v"(r) : "v"(lo), "v"(hi));
  return r;
}
__device__ __forceinline__ float bf_lo(u32 u){ union{u32 a; float f;} x; x.a = u << 16;        return x.f; }
__device__ __forceinline__ float bf_hi(u32 u){ union{u32 a; float f;} x; x.a = u & 0xffff0000u; return x.f; }

__device__ __forceinline__ float sigm(float x)   { return 1.0f / (1.0f + __expf(-x)); }
__device__ __forceinline__ float tanh_f(float x) { return 1.0f - 2.0f / (__expf(2.0f * x) + 1.0f); }

// =====================================================================
// Kernel 1: x_proj = x @ Wih^T + bih  -> bf16, layout [dir][m=t*8+b][1024]
// (plain layout, no swizzle: consumer loads straight to registers)
// =====================================================================
__global__ __launch_bounds__(256) void xproj_gemm(
    const float* __restrict__ x,
    const float* __restrict__ WihF, const float* __restrict__ bihF,
    const float* __restrict__ WihB, const float* __restrict__ bihB,
    uint16_t* __restrict__ xp)
{
  const int dir = blockIdx.z;
  const float* Wih = dir ? WihB : WihF;
  const float* bih = dir ? bihB : bihF;
  char* xpd = (char*)xp + (size_t)dir * ((size_t)NROW * G4 * 2);

  const int g0 = blockIdx.y * 128;
  const int m0 = blockIdx.x * 128;

  __shared__ union {
    struct { short A[128 * 72]; short B[128 * 72]; } s;  // 144B row pitch
    short T[128 * 136];                                  // transpose stage
  } u;
  __shared__ float biasS[128];

  const int tid  = threadIdx.x;
  const int lane = tid & 63;
  const int w    = tid >> 6;
  const int wg   = w >> 1;
  const int wm   = w & 1;
  const int l15  = lane & 15;
  const int l4   = lane >> 4;

  if (tid < 128) biasS[tid] = bih[g0 + tid];

  f32x4 acc[4][4] = {};

  const int r_st = tid >> 1;
  const int half = tid & 1;
  const int mrow_st = m0 + r_st;
  const int xb = mrow_st & 7;
  const int xt = mrow_st >> 3;
  const float* xrow = x + ((size_t)xb * SQ + xt) * 256;
  const float* wrow = Wih + (size_t)(g0 + r_st) * 256;

  for (int s = 0; s < 4; ++s) {
    const int k0 = s * 64;
    __syncthreads();
    {
      const float* srcA = wrow + k0 + half * 32;
      const float* srcB = xrow + k0 + half * 32;
      short* dstA = u.s.A + r_st * 72 + half * 32;
      short* dstB = u.s.B + r_st * 72 + half * 32;
      #pragma unroll
      for (int j = 0; j < 4; ++j) {
        f32x4 a0 = *(const f32x4*)(srcA + j * 8);
        f32x4 a1 = *(const f32x4*)(srcA + j * 8 + 4);
        uint4 pa = { pk_bf16(a0.x, a0.y), pk_bf16(a0.z, a0.w),
                     pk_bf16(a1.x, a1.y), pk_bf16(a1.z, a1.w) };
        *(uint4*)(dstA + j * 8) = pa;
        f32x4 b0 = *(const f32x4*)(srcB + j * 8);
        f32x4 b1 = *(const f32x4*)(srcB + j * 8 + 4);
        uint4 pb = { pk_bf16(b0.x, b0.y), pk_bf16(b0.z, b0.w),
                     pk_bf16(b1.x, b1.y), pk_bf16(b1.z, b1.w) };
        *(uint4*)(dstB + j * 8) = pb;
      }
    }
    __syncthreads();
    #pragma unroll
    for (int kt = 0; kt < 2; ++kt) {
      bf16x8 aF[4], bF[4];
      #pragma unroll
      for (int i = 0; i < 4; ++i) {
        const int ar = wg * 64 + i * 16 + l15;
        const int br = wm * 64 + i * 16 + l15;
        aF[i] = *(const bf16x8*)(u.s.A + ar * 72 + kt * 32 + l4 * 8);
        bF[i] = *(const bf16x8*)(u.s.B + br * 72 + kt * 32 + l4 * 8);
      }
      #pragma unroll
      for (int i = 0; i < 4; ++i)
        #pragma unroll
        for (int j = 0; j < 4; ++j)
          acc[i][j] = mfma16(aF[i], bF[j], acc[i][j]);
    }
  }

  __syncthreads();
  #pragma unroll
  for (int i = 0; i < 4; ++i) {
    const f32x4 bv = *(const f32x4*)(biasS + wg * 64 + i * 16 + l4 * 4);
    #pragma unroll
    for (int j = 0; j < 4; ++j) {
      f32x4 v = acc[i][j];
      v.x += bv.x; v.y += bv.y; v.z += bv.z; v.w += bv.w;
      const int mrow = wm * 64 + j * 16 + l15;
      const int gcol = wg * 64 + i * 16 + l4 * 4;
      uint2 p; p.x = pk_bf16(v.x, v.y); p.y = pk_bf16(v.z, v.w);
      *(uint2*)(u.T + mrow * 136 + gcol) = p;
    }
  }
  __syncthreads();
  {
    const char* trow = (const char*)(u.T + r_st * 136);
    char* orow = xpd + (size_t)(m0 + r_st) * 2048 + g0 * 2;
    #pragma unroll
    for (int j = 0; j < 8; ++j) {
      const int local = half * 128 + j * 16;
      uint4 v = *(const uint4*)(trow + local);
      *(uint4*)(orow + local) = v;
    }
  }
}

// =====================================================================
// Kernel 2: bidirectional LSTM scan, 2 WGs per direction (row-split).
// Each WG: 128 h-rows x 4 gates = 32 M-tiles, ALL weights in VGPRs
// (64 bf16x8 = 256 regs/wave). h-halves exchanged through `out` (f32),
// guarded by per-wave release atomicAdd flags + acquire polling.
// Pairs placed on same XCD via bid&7 heuristic (grid=16, 12 blocks idle).
// =====================================================================
template<int HALF>
__device__ __forceinline__ void lstm_body(
    const float* __restrict__ Whh, const uint16_t* __restrict__ xpd,
    float* out, u32* flg_partner, u32* flg_mine, int dir,
    uint16_t (*hT)[8][136])
{
  const int tid  = threadIdx.x;
  const int lane = tid & 63;
  const int w    = tid >> 6;
  const int l15  = lane & 15;
  const int l4   = lane >> 4;
  const int bcl  = lane & 7;
  const int qsel = (lane >> 3) & 1;

  // ---- persistent weight fragments: Wr[gate][T][kt], rows of this half
  bf16x8 Wr[4][2][8];
  #pragma unroll
  for (int g = 0; g < 4; ++g) {
    #pragma unroll
    for (int T = 0; T < 2; ++T) {
      const int row = g * 256 + HALF * 128 + w * 32 + T * 16 + l15;
      const float* src = Whh + (size_t)row * 256 + l4 * 8;
      #pragma unroll
      for (int kt = 0; kt < 8; ++kt) {
        f32x4 v0 = *(const f32x4*)(src + kt * 32);
        f32x4 v1 = *(const f32x4*)(src + kt * 32 + 4);
        union { bf16x8 v; u32 u[4]; } pk;
        pk.u[0] = pk_bf16(v0.x, v0.y); pk.u[1] = pk_bf16(v0.z, v0.w);
        pk.u[2] = pk_bf16(v1.x, v1.y); pk.u[3] = pk_bf16(v1.z, v1.w);
        Wr[g][T][kt] = pk.v;
      }
    }
  }

  for (int i = tid; i < 2 * 8 * 136; i += 256) ((uint16_t*)hT)[i] = 0;

  float cst[4] = {0, 0, 0, 0};
  const int colbase = HALF * 128 + w * 32 + qsel * 16 + l4 * 4;   // h-row this lane owns
  __syncthreads();

  // prologue: xp for step 0
  uint2 xq[4];
  {
    const int tt0 = dir ? (SQ - 1) : 0;
    const uint16_t* xrow = xpd + (size_t)(tt0 * 8 + bcl) * 1024;
    #pragma unroll
    for (int g = 0; g < 4; ++g) xq[g] = *(const uint2*)(xrow + g * 256 + colbase);
  }

  #pragma unroll 1
  for (int t = 0; t < SQ; ++t) {
    const int tt = dir ? (SQ - 1 - t) : t;

    // ---- partner h: poll flag, then vector loads from `out`
    f32x4 ph[4][2];
    if (t > 0) {
      u32* fl = flg_partner + (t - 1);
      while (__hip_atomic_load(fl, __ATOMIC_ACQUIRE, __HIP_MEMORY_SCOPE_AGENT) < 4u) {}
      const int tp = dir ? (SQ - t) : (t - 1);
      const float* psrc = out + ((size_t)bcl * SQ + tp) * 512 + dir * 256 + (1 - HALF) * 128;
      #pragma unroll
      for (int j = 0; j < 4; ++j) {
        ph[j][0] = *(const f32x4*)(psrc + j * 32 + l4 * 8);
        ph[j][1] = *(const f32x4*)(psrc + j * 32 + l4 * 8 + 4);
      }
    } else {
      #pragma unroll
      for (int j = 0; j < 4; ++j) {
        ph[j][0] = f32x4{0, 0, 0, 0};
        ph[j][1] = f32x4{0, 0, 0, 0};
      }
    }

    // ---- K-own: h-half from LDS (written by this WG last step)
    f32x4 acc[4][2] = {};
    #pragma unroll
    for (int j = 0; j < 4; ++j) {
      const bf16x8 bF = *(const bf16x8*)&hT[t & 1][bcl][j * 32 + l4 * 8];
      #pragma unroll
      for (int g = 0; g < 4; ++g) {
        acc[g][0] = mfma16(Wr[g][0][HALF * 4 + j], bF, acc[g][0]);
        acc[g][1] = mfma16(Wr[g][1][HALF * 4 + j], bF, acc[g][1]);
      }
    }

    // ---- K-other: partner h from regs (pack f32->bf16)
    #pragma unroll
    for (int j = 0; j < 4; ++j) {
      union { bf16x8 v; u32 u[4]; } pb;
      pb.u[0] = pk_bf16(ph[j][0].x, ph[j][0].y); pb.u[1] = pk_bf16(ph[j][0].z, ph[j][0].w);
      pb.u[2] = pk_bf16(ph[j][1].x, ph[j][1].y); pb.u[3] = pk_bf16(ph[j][1].z, ph[j][1].w);
      #pragma unroll
      for (int g = 0; g < 4; ++g) {
        acc[g][0] = mfma16(Wr[g][0][(1 - HALF) * 4 + j], pb.v, acc[g][0]);
        acc[g][1] = mfma16(Wr[g][1][(1 - HALF) * 4 + j], pb.v, acc[g][1]);
      }
    }

    // ---- P = selected tile (cols 8-15 duplicate 0-7: no cross-lane moves) + xp
    float P[4][4];
    #pragma unroll
    for (int g = 0; g < 4; ++g) {
      const uint2 d = xq[g];
      P[g][0] = (qsel ? acc[g][1].x : acc[g][0].x) + bf_lo(d.x);
      P[g][1] = (qsel ? acc[g][1].y : acc[g][0].y) + bf_hi(d.x);
      P[g][2] = (qsel ? acc[g][1].z : acc[g][0].z) + bf_lo(d.y);
      P[g][3] = (qsel ? acc[g][1].w : acc[g][0].w) + bf_hi(d.y);
    }

    // ---- activations + state
    float hv[4];
    #pragma unroll
    for (int e = 0; e < 4; ++e) {
      const float iv = sigm(P[0][e]);
      const float fv = sigm(P[1][e]);
      const float gv = tanh_f(P[2][e]);
      const float ov = sigm(P[3][e]);
      const float cv = fv * cst[e] + iv * gv;
      cst[e] = cv;
      hv[e] = ov * tanh_f(cv);
    }

    // ---- h out (f32, also the exchange medium) + own-half LDS write
    f32x4 hvv = { hv[0], hv[1], hv[2], hv[3] };
    *(f32x4*)(out + ((size_t)bcl * SQ + tt) * 512 + dir * 256 + colbase) = hvv;
    uint2 hp; hp.x = pk_bf16(hv[0], hv[1]); hp.y = pk_bf16(hv[2], hv[3]);
    *(uint2*)&hT[(t + 1) & 1][bcl][w * 32 + qsel * 16 + l4 * 4] = hp;

    // one barrier per step: drains h-store (vmcnt0) + hT write (lgkm0)
    __syncthreads();

    // release: one fetch_add per wave (orders that wave's drained stores)
    if (lane == 0)
      __hip_atomic_fetch_add(flg_mine + t, 1u, __ATOMIC_RELEASE, __HIP_MEMORY_SCOPE_AGENT);

    // issue next step's xp loads (post-barrier so the barrier doesn't drain them)
    {
      const int tn = (t + 1 < SQ) ? (t + 1) : (SQ - 1);
      const int ttn = dir ? (SQ - 1 - tn) : tn;
      const uint16_t* xrow = xpd + (size_t)(ttn * 8 + bcl) * 1024;
      #pragma unroll
      for (int g = 0; g < 4; ++g) xq[g] = *(const uint2*)(xrow + g * 256 + colbase);
    }
  }
}

__global__ __launch_bounds__(256, 1) void lstm_rec(
    const float* __restrict__ WhhF, const float* __restrict__ WhhB,
    const uint16_t* __restrict__ xp, float* out, u32* flags)
{
  __shared__ uint16_t hT[2][8][136];

  const int bid  = blockIdx.x;
  const int xcd  = bid & 7;
  const int slot = bid >> 3;
  if (xcd > 1) return;                 // 12 idle blocks exit immediately
  const int dir = xcd, half = slot;    // pair (half 0,1) of a dir on same XCD

  const float* Whh = dir ? WhhB : WhhF;
  const uint16_t* xpd = xp + (size_t)dir * NROW * G4;
  u32* fp = flags + (size_t)(dir * 2 + (1 - half)) * SQ;
  u32* fm = flags + (size_t)(dir * 2 + half) * SQ;

  if (half == 0) lstm_body<0>(Whh, xpd, out, fp, fm, dir, hT);
  else           lstm_body<1>(Whh, xpd, out, fp, fm, dir, hT);
}

// =====================================================================
extern "C" void kernel_launch(void* const* d_in, const int* in_sizes, int n_in,
                              void* d_out, int out_size, void* d_ws, size_t ws_size,
                              hipStream_t stream) {
  const float* x    = (const float*)d_in[0];
  const float* WihF = (const float*)d_in[1];
  const float* bihF = (const float*)d_in[2];
  const float* WhhF = (const float*)d_in[3];
  const float* WihB = (const float*)d_in[4];
  const float* bihB = (const float*)d_in[5];
  const float* WhhB = (const float*)d_in[6];
  float* out = (float*)d_out;

  const size_t XPB = (size_t)2 * NROW * G4 * 2;     // 64 MiB bf16 x-projection
  const size_t FLB = (size_t)2 * 2 * SQ * sizeof(u32);
  if (ws_size < XPB + FLB) return;
  uint16_t* xpw = (uint16_t*)d_ws;
  u32* flags = (u32*)((char*)d_ws + XPB);

  hipMemsetAsync(flags, 0, FLB, stream);
  xproj_gemm<<<dim3(128, 8, 2), dim3(256), 0, stream>>>(x, WihF, bihF, WihB, bihB, xpw);
  lstm_rec<<<dim3(16), dim3(256), 0, stream>>>(WhhF, WhhB, xpw, out, flags);
}